// Round 18
// baseline (1190.352 us; speedup 1.0000x reference)
//
#include <hip/hip_runtime.h>

typedef unsigned short u16;
typedef unsigned int u32;

__device__ __forceinline__ float bf2f(u16 u){ union{u32 i; float f;} v; v.i=((u32)u)<<16; return v.f; }
__device__ __forceinline__ float bflo(u32 p){ union{u32 i; float f;} v; v.i=p<<16; return v.f; }
__device__ __forceinline__ float bfhi(u32 p){ union{u32 i; float f;} v; v.i=p&0xffff0000u; return v.f; }
__device__ __forceinline__ u16 f2bf(float x){ union{float f; u32 i;} v; v.f=x; u32 b=v.i;
  return (u16)((b + 0x7fffu + ((b>>16)&1u))>>16); }
__device__ __forceinline__ u32 pk2(float a, float b){ return ((u32)f2bf(b)<<16) | (u32)f2bf(a); }

#define HEADS 4
#define HHID 256   // HEADS*HID
#define NT 16      // nodes per tile in k_xlr

// ---- fill d_out with a float value (diagnostic only) ----
__global__ void TopoAggregator_33217277067466_kernel(float* __restrict__ out, int n, float val){
  for(int i = blockIdx.x*blockDim.x + threadIdx.x; i < n; i += gridDim.x*blockDim.x)
    out[i] = val;
}

// ---- post-hoc invariant marker: touches d_out ONLY on failure ----
__global__ void k_marker(const int* __restrict__ rowstart, const float* __restrict__ h,
                         float* __restrict__ out, int N, int E){
  if(threadIdx.x!=0 || blockIdx.x!=0) return;
  float M = 0.f;
  if(rowstart[N] != E) M = 400.f;
  else {
    int allz = 1;
    for(int i=0;i<128;i++) if(h[i]!=0.f){ allz=0; break; }
    if(allz) M = 500.f;
  }
  if(M != 0.f) out[0] = M;
}

// ---- zero counts[N] and relmean[16] ----
__global__ void k_zero(int* __restrict__ counts, float* __restrict__ relmean, int N){
  int i = blockIdx.x*blockDim.x + threadIdx.x;
  if(i < N) counts[i] = 0;
  if(i < 16) relmean[i] = 0.f;
}

// ---- relation mean over E rows of 16 (f32) ----
__global__ void k_relmean(const float* __restrict__ rel, float* __restrict__ relmean, int E){
  __shared__ float red[256][16];
  float s[16];
#pragma unroll
  for(int j=0;j<16;j++) s[j]=0.f;
  for(int r = blockIdx.x*blockDim.x + threadIdx.x; r < E; r += gridDim.x*blockDim.x){
    const float4* p = (const float4*)(rel + (size_t)r*16);
    float4 a=p[0], b=p[1], c=p[2], d=p[3];
    s[0]+=a.x; s[1]+=a.y; s[2]+=a.z; s[3]+=a.w;
    s[4]+=b.x; s[5]+=b.y; s[6]+=b.z; s[7]+=b.w;
    s[8]+=c.x; s[9]+=c.y; s[10]+=c.z; s[11]+=c.w;
    s[12]+=d.x; s[13]+=d.y; s[14]+=d.z; s[15]+=d.w;
  }
  int tid = threadIdx.x;
#pragma unroll
  for(int j=0;j<16;j++) red[tid][j]=s[j];
  __syncthreads();
  for(int off=128; off>0; off>>=1){
    if(tid<off){
#pragma unroll
      for(int j=0;j<16;j++) red[tid][j]+=red[tid+off][j];
    }
    __syncthreads();
  }
  if(tid<16) atomicAdd(relmean+tid, red[0][tid]*(1.0f/(float)E));
}

// ---- CSR build over REAL edges only (self-loops handled analytically) ----
__global__ void k_count(const int* __restrict__ edges, int* __restrict__ counts, int E, int N){
  int e = blockIdx.x*blockDim.x + threadIdx.x;
  if(e>=E) return;
  int d = edges[E+e];
  if(d<0) d=0; if(d>=N) d=N-1;
  atomicAdd(counts+d, 1);
}

// ---- 3-phase parallel exclusive scan over counts[N] ----
#define STILE 1024
__global__ void k_scan_a(const int* __restrict__ counts, int* __restrict__ tilesum, int N){
  __shared__ int red[256];
  int base = blockIdx.x*STILE;
  int tid = threadIdx.x;
  int s = 0;
  for(int i=tid; i<STILE; i+=256){
    int idx = base + i;
    s += (idx < N) ? counts[idx] : 0;
  }
  red[tid] = s;
  __syncthreads();
  for(int off=128; off>0; off>>=1){
    if(tid<off) red[tid] += red[tid+off];
    __syncthreads();
  }
  if(tid==0) tilesum[blockIdx.x] = red[0];
}

__global__ void k_scan_b(const int* __restrict__ tilesum, int* __restrict__ tileoff, int nT){
  __shared__ int buf[1024];
  int tid = threadIdx.x;
  buf[tid] = (tid < nT) ? tilesum[tid] : 0;
  __syncthreads();
  for(int off=1; off<1024; off<<=1){
    int v = (tid>=off) ? buf[tid-off] : 0;
    __syncthreads();
    buf[tid] += v;
    __syncthreads();
  }
  if(tid < nT) tileoff[tid] = (tid==0) ? 0 : buf[tid-1];
}

__global__ void k_scan_c(const int* __restrict__ counts, const int* __restrict__ tileoff,
                         int* __restrict__ rowstart, int* __restrict__ cursor, int N){
  __shared__ int buf[STILE];
  int base = blockIdx.x*STILE;
  int tid = threadIdx.x;
  int idx = base + tid;
  int c = (idx < N) ? counts[idx] : 0;
  buf[tid] = c;
  __syncthreads();
  for(int off=1; off<1024; off<<=1){
    int v = (tid>=off) ? buf[tid-off] : 0;
    __syncthreads();
    buf[tid] += v;
    __syncthreads();
  }
  int excl = buf[tid] - c + tileoff[blockIdx.x];
  if(idx < N){ rowstart[idx]=excl; cursor[idx]=excl; }
  if(idx == N-1) rowstart[N] = excl + c;
}

// scatter src AND the rel row (packed bf16, CSR order)
__global__ void k_scatter(const int* __restrict__ edges, const float* __restrict__ relation,
                          int* __restrict__ cursor,
                          int* __restrict__ adj_src, u32* __restrict__ rel_s, int E, int N){
  int e = blockIdx.x*blockDim.x + threadIdx.x;
  if(e>=E) return;
  int s = edges[e], d = edges[E+e];
  if(d<0) d=0; if(d>=N) d=N-1;
  int pos = atomicAdd(cursor+d, 1);
  adj_src[pos]=s;
  const float4* rp = (const float4*)(relation + (size_t)e*16);
  float4 q0=rp[0], q1=rp[1], q2=rp[2], q3=rp[3];
  uint4* dst = (uint4*)(rel_s + (size_t)pos*8);
  dst[0] = make_uint4(pk2(q0.x,q0.y), pk2(q0.z,q0.w), pk2(q1.x,q1.y), pk2(q1.z,q1.w));
  dst[1] = make_uint4(pk2(q2.x,q2.y), pk2(q2.z,q2.w), pk2(q3.x,q3.y), pk2(q3.z,q3.w));
}

// ---- embedding + input projection: h[N][64] (f32) ----
__global__ void k_embed(const float* __restrict__ nodes,
                        const float* __restrict__ time_emb, const float* __restrict__ type_emb,
                        const float* __restrict__ biway_emb, const float* __restrict__ islink_emb,
                        const float* __restrict__ projw, const float* __restrict__ projb,
                        float* __restrict__ h, int N){
  __shared__ float W[64][65];
  __shared__ float h0[4][64];
  int tid = threadIdx.x;
  for(int i=tid; i<64*64; i+=256) W[i>>6][i&63] = projw[i];
  __syncthreads();
  int wave = tid>>6, lane = tid&63;
  int node = blockIdx.x*4 + wave;
  if(node<N){
    const float* nr = nodes + (size_t)node*20;
    float v; int c = lane;
    if(c<16){
      int t=(int)nr[0]; t = t<0?0:(t>287?287:t);
      v = time_emb[t*16+c];
    } else if(c<32){
      int ty=(int)nr[1]; ty = ty<0?0:(ty>15?15:ty);
      v = type_emb[ty*16+(c-16)];
    } else if(c<40){
      int bw=(int)nr[2]; bw = bw<0?0:(bw>1?1:bw);
      v = biway_emb[bw*8+(c-32)];
    } else if(c<48){
      int il=(int)nr[3]; il = il<0?0:(il>1?1:il);
      v = islink_emb[il*8+(c-40)];
    } else {
      v = nr[4 + (c-48)];
    }
    h0[wave][lane]=v;
  }
  __syncthreads();
  if(node<N){
    float acc = projb[lane];
#pragma unroll
    for(int k=0;k<64;k++) acc += W[lane][k]*h0[wave][k];
    h[(size_t)node*64+lane]=acc;
  }
}

// ---- xl/xr: grid-strided, weights resident in registers.
// First half of grid computes xl (wl), second half xr (wr).
__global__ void __launch_bounds__(256)
k_xlr(const float* __restrict__ h,
      const float* __restrict__ wl, const float* __restrict__ bl,
      const float* __restrict__ wr, const float* __restrict__ br,
      u16* __restrict__ xl, u16* __restrict__ xr, int N, int nTiles){
  const int half = gridDim.x >> 1;
  const bool isR = (blockIdx.x >= half);
  const float* wsel = isR ? wr : wl;
  const float* bsel = isR ? br : bl;
  u16* xout = isR ? xr : xl;
  const int b0 = isR ? (blockIdx.x - half) : blockIdx.x;
  const int o = threadIdx.x;
  float4 wreg[16];
  {
    const float4* wp = (const float4*)(wsel + (size_t)o*64);
#pragma unroll
    for(int i=0;i<16;i++) wreg[i]=wp[i];
  }
  const float bv = bsel[o];
  __shared__ float hs[NT*64];
  for(int t=b0; t<nTiles; t+=half){
    int base = t*NT;
    int nvalid = N - base; if(nvalid > NT) nvalid = NT;
    if(nvalid == NT){
      *(float4*)(hs + o*4) = *(const float4*)(h + (size_t)base*64 + o*4);
    } else {
      for(int i=o; i<NT*64; i+=256) hs[i] = (i < nvalid*64) ? h[(size_t)base*64+i] : 0.f;
    }
    __syncthreads();
    float acc[NT];
#pragma unroll
    for(int n=0;n<NT;n++) acc[n]=bv;
#pragma unroll
    for(int kk=0; kk<16; kk++){
      float4 a = wreg[kk];
#pragma unroll
      for(int n=0;n<NT;n++){
        float4 hv = *(const float4*)(hs + n*64 + kk*4);
        acc[n] += a.x*hv.x + a.y*hv.y + a.z*hv.z + a.w*hv.w;
      }
    }
    for(int n=0;n<nvalid;n++)
      xout[(size_t)(base+n)*HHID + o] = f2bf(acc[n]);
    __syncthreads();
  }
}

// ---- fused per-node: PAIRED edge processing sharing weT LDS reads ----
// 16 LDS b128 reads feed TWO edges (8 reads/edge); 1-pair-ahead data prefetch,
// 2-pair-ahead index prefetch; odd tail handled branchlessly (c=-1e30 -> wgt=0).
__global__ void __launch_bounds__(256)
k_fused(const int* __restrict__ rowstart, const int* __restrict__ adj_src,
        const u32* __restrict__ rel_s, const float* __restrict__ relmean,
        const float* __restrict__ we, const float* __restrict__ att,
        const u16* __restrict__ xl, const u16* __restrict__ xr,
        const float* __restrict__ gat_b,
        float* __restrict__ h, int N, float* __restrict__ outp){
  __shared__ float weT[16*256];   // [k][ch]
  {
    int tid = threadIdx.x;
    for(int i=tid; i<16*256; i+=256){
      int k = i >> 8, ch = i & 255;
      weT[k*256 + ch] = we[(size_t)ch*16 + k];
    }
  }
  __syncthreads();
  const int lane = threadIdx.x & 63;
  const int sub = lane & 15;
  const int wid = (blockIdx.x*blockDim.x + threadIdx.x) >> 6;
  const int nw  = (gridDim.x*blockDim.x) >> 6;
  const float4* wT4 = (const float4*)weT;   // index: k*64 + lane

  const float4 at4 = *(const float4*)(att + lane*4);

  // self-loop ep (per-wave constant)
  float es0=0.f, es1=0.f, es2=0.f, es3=0.f;
#pragma unroll
  for(int k=0;k<16;k++){
    float rmk = relmean[k];
    float4 w4 = wT4[k*64 + lane];
    es0 += rmk*w4.x; es1 += rmk*w4.y; es2 += rmk*w4.z; es3 += rmk*w4.w;
  }

  for(int node = wid; node < N; node += nw){
    const int lo = rowstart[node], hi = rowstart[node+1];
    uint2 pb = *(const uint2*)(xr + (size_t)node*HHID + lane*4);
    float bv0=bflo(pb.x), bv1=bfhi(pb.x), bv2=bflo(pb.y), bv3=bfhi(pb.y);

    // self-loop initializes online softmax
    float m, den, a0, a1, a2, a3;
    {
      uint2 ps = *(const uint2*)(xl + (size_t)node*HHID + lane*4);
      float sv0=bflo(ps.x), sv1=bfhi(ps.x), sv2=bflo(ps.y), sv3=bfhi(ps.y);
      float c = 0.f;
      {
        float mm;
        mm = sv0 + bv0 + es0; mm = (mm>0.f)?mm:0.2f*mm; c += mm*at4.x;
        mm = sv1 + bv1 + es1; mm = (mm>0.f)?mm:0.2f*mm; c += mm*at4.y;
        mm = sv2 + bv2 + es2; mm = (mm>0.f)?mm:0.2f*mm; c += mm*at4.z;
        mm = sv3 + bv3 + es3; mm = (mm>0.f)?mm:0.2f*mm; c += mm*at4.w;
      }
      c += __shfl_xor(c, 1);
      c += __shfl_xor(c, 2);
      c += __shfl_xor(c, 4);
      c += __shfl_xor(c, 8);
      m = c; den = 1.f;
      a0 = sv0; a1 = sv1; a2 = sv2; a3 = sv3;
    }

    if(lo < hi){
      // index prefetch for pair0 and pair1
      int sA1 = (lo+2<hi) ? adj_src[lo+2] : 0;
      int sB1 = (lo+3<hi) ? adj_src[lo+3] : 0;
      // data for pair0
      uint4 rA0c, rA1c; uint2 paAc;
      {
        int sv = adj_src[lo]; if(sv<0) sv=0; if(sv>=N) sv=N-1;
        const uint4* rp = (const uint4*)(rel_s + (size_t)lo*8);
        rA0c = rp[0]; rA1c = rp[1];
        paAc = *(const uint2*)(xl + (size_t)sv*HHID + lane*4);
      }
      uint4 rB0c = make_uint4(0,0,0,0), rB1c = rB0c; uint2 paBc = make_uint2(0u,0u);
      if(lo+1 < hi){
        int sv = adj_src[lo+1]; if(sv<0) sv=0; if(sv>=N) sv=N-1;
        const uint4* rp = (const uint4*)(rel_s + (size_t)(lo+1)*8);
        rB0c = rp[0]; rB1c = rp[1];
        paBc = *(const uint2*)(xl + (size_t)sv*HHID + lane*4);
      }

      for(int p=lo; p<hi; p+=2){
        // stage 1: data prefetch for pair p+2 (indices resident)
        uint4 rA0n = make_uint4(0,0,0,0), rA1n = rA0n, rB0n = rA0n, rB1n = rA0n;
        uint2 paAn = make_uint2(0u,0u), paBn = paAn;
        if(p+2 < hi){
          int sv = sA1; if(sv<0) sv=0; if(sv>=N) sv=N-1;
          const uint4* rp = (const uint4*)(rel_s + (size_t)(p+2)*8);
          rA0n = rp[0]; rA1n = rp[1];
          paAn = *(const uint2*)(xl + (size_t)sv*HHID + lane*4);
          if(p+3 < hi){
            int sv2 = sB1; if(sv2<0) sv2=0; if(sv2>=N) sv2=N-1;
            const uint4* rp2 = (const uint4*)(rel_s + (size_t)(p+3)*8);
            rB0n = rp2[0]; rB1n = rp2[1];
            paBn = *(const uint2*)(xl + (size_t)sv2*HHID + lane*4);
          }
        }
        // stage 2: index prefetch for pair p+4
        int sA2 = (p+4<hi) ? adj_src[p+4] : 0;
        int sB2 = (p+5<hi) ? adj_src[p+5] : 0;

        // stage 3: compute edges p and p+1 sharing weT reads
        float eA0=0.f,eA1=0.f,eA2=0.f,eA3=0.f, eB0=0.f,eB1=0.f,eB2=0.f,eB3=0.f;
#define EPW2(WA, WB, KB) { \
        float al=bflo(WA), ah=bfhi(WA), bl_=bflo(WB), bh_=bfhi(WB); \
        float4 wa = wT4[(KB)*64 + lane]; \
        float4 wb = wT4[(KB+1)*64 + lane]; \
        eA0 += al*wa.x + ah*wb.x;  eB0 += bl_*wa.x + bh_*wb.x; \
        eA1 += al*wa.y + ah*wb.y;  eB1 += bl_*wa.y + bh_*wb.y; \
        eA2 += al*wa.z + ah*wb.z;  eB2 += bl_*wa.z + bh_*wb.z; \
        eA3 += al*wa.w + ah*wb.w;  eB3 += bl_*wa.w + bh_*wb.w; }
        EPW2(rA0c.x, rB0c.x, 0)  EPW2(rA0c.y, rB0c.y, 2)
        EPW2(rA0c.z, rB0c.z, 4)  EPW2(rA0c.w, rB0c.w, 6)
        EPW2(rA1c.x, rB1c.x, 8)  EPW2(rA1c.y, rB1c.y,10)
        EPW2(rA1c.z, rB1c.z,12)  EPW2(rA1c.w, rB1c.w,14)
#undef EPW2

        float avA0=bflo(paAc.x), avA1=bfhi(paAc.x), avA2=bflo(paAc.y), avA3=bfhi(paAc.y);
        float avB0=bflo(paBc.x), avB1=bfhi(paBc.x), avB2=bflo(paBc.y), avB3=bfhi(paBc.y);
        float cA = 0.f, cB = 0.f;
        {
          float mm;
          mm = avA0 + bv0 + eA0; mm=(mm>0.f)?mm:0.2f*mm; cA += mm*at4.x;
          mm = avA1 + bv1 + eA1; mm=(mm>0.f)?mm:0.2f*mm; cA += mm*at4.y;
          mm = avA2 + bv2 + eA2; mm=(mm>0.f)?mm:0.2f*mm; cA += mm*at4.z;
          mm = avA3 + bv3 + eA3; mm=(mm>0.f)?mm:0.2f*mm; cA += mm*at4.w;
          mm = avB0 + bv0 + eB0; mm=(mm>0.f)?mm:0.2f*mm; cB += mm*at4.x;
          mm = avB1 + bv1 + eB1; mm=(mm>0.f)?mm:0.2f*mm; cB += mm*at4.y;
          mm = avB2 + bv2 + eB2; mm=(mm>0.f)?mm:0.2f*mm; cB += mm*at4.z;
          mm = avB3 + bv3 + eB3; mm=(mm>0.f)?mm:0.2f*mm; cB += mm*at4.w;
        }
        cA += __shfl_xor(cA, 1); cB += __shfl_xor(cB, 1);
        cA += __shfl_xor(cA, 2); cB += __shfl_xor(cB, 2);
        cA += __shfl_xor(cA, 4); cB += __shfl_xor(cB, 4);
        cA += __shfl_xor(cA, 8); cB += __shfl_xor(cB, 8);
        if(p+1 >= hi) cB = -1e30f;   // invalid tail edge -> weight 0

        // online softmax update, edge A then edge B
        if(cA > m){
          float sc = __expf(m - cA);
          den *= sc; a0 *= sc; a1 *= sc; a2 *= sc; a3 *= sc;
          m = cA;
        }
        float wA = __expf(cA - m);
        den += wA;
        a0 += wA*avA0; a1 += wA*avA1; a2 += wA*avA2; a3 += wA*avA3;

        if(cB > m){
          float sc = __expf(m - cB);
          den *= sc; a0 *= sc; a1 *= sc; a2 *= sc; a3 *= sc;
          m = cB;
        }
        float wB = __expf(cB - m);
        den += wB;
        a0 += wB*avB0; a1 += wB*avB1; a2 += wB*avB2; a3 += wB*avB3;

        // rotate pipeline
        rA0c = rA0n; rA1c = rA1n; rB0c = rB0n; rB1c = rB1n;
        paAc = paAn; paBc = paBn;
        sA1 = sA2; sB1 = sB2;
      }
    }

    float inv = 1.0f/den;
    float v0=a0*inv, v1=a1*inv, v2=a2*inv, v3=a3*inv;
    v0 += __shfl_xor(v0,16); v0 += __shfl_xor(v0,32);
    v1 += __shfl_xor(v1,16); v1 += __shfl_xor(v1,32);
    v2 += __shfl_xor(v2,16); v2 += __shfl_xor(v2,32);
    v3 += __shfl_xor(v3,16); v3 += __shfl_xor(v3,32);
    if(lane < 16){
      int cb = sub*4;
      float4 hv = *(const float4*)(h + (size_t)node*64 + cb);
      const float4 gb = *(const float4*)(gat_b + cb);
      float o0 = fmaxf(0.25f*v0 + gb.x + hv.x, 0.f);
      float o1 = fmaxf(0.25f*v1 + gb.y + hv.y, 0.f);
      float o2 = fmaxf(0.25f*v2 + gb.z + hv.z, 0.f);
      float o3 = fmaxf(0.25f*v3 + gb.w + hv.w, 0.f);
      *(float4*)(h + (size_t)node*64 + cb) = make_float4(o0,o1,o2,o3);
      if(outp) *(float4*)(outp + (size_t)node*64 + cb) = make_float4(o0,o1,o2,o3);
    }
  }
}

extern "C" void kernel_launch(void* const* d_in, const int* in_sizes, int n_in,
                              void* d_out, int out_size, void* d_ws, size_t ws_size,
                              hipStream_t stream) {
  const float* nodes     = (const float*)d_in[0];
  const int*   edges     = (const int*)d_in[1];
  const float* relation  = (const float*)d_in[2];
  const float* time_emb  = (const float*)d_in[3];
  const float* type_emb  = (const float*)d_in[4];
  const float* biway_emb = (const float*)d_in[5];
  const float* islink_emb= (const float*)d_in[6];
  const float* proj_w    = (const float*)d_in[7];
  const float* proj_b    = (const float*)d_in[8];
  const float* lin_l_w   = (const float*)d_in[9];
  const float* lin_l_b   = (const float*)d_in[10];
  const float* lin_r_w   = (const float*)d_in[11];
  const float* lin_r_b   = (const float*)d_in[12];
  const float* lin_e_w   = (const float*)d_in[13];
  const float* att       = (const float*)d_in[14];
  const float* gat_b     = (const float*)d_in[15];

  const int N  = in_sizes[0] / 20;
  const int E  = in_sizes[1] / 2;
  const int nT = (N + STILE - 1) / STILE;
  const int nTiles = (N + NT - 1) / NT;

  size_t off = 0;
  auto alloc = [&](size_t bytes)->size_t {
    size_t p = off;
    off += ((bytes + 255) / 256) * 256;
    return p;
  };
  size_t o_h        = alloc((size_t)N*64*4);        // f32
  size_t o_xl       = alloc((size_t)N*HHID*2);      // bf16
  size_t o_xr       = alloc((size_t)N*HHID*2);      // bf16
  size_t o_rels     = alloc((size_t)E*32);          // bf16 rel rows, CSR order
  size_t o_relmean  = alloc(64*4);
  size_t o_counts   = alloc((size_t)N*4);
  size_t o_rowstart = alloc((size_t)(N+1)*4);
  size_t o_cursor   = alloc((size_t)(N+1)*4);
  size_t o_adjsrc   = alloc((size_t)E*4);
  size_t o_tilesum  = alloc((size_t)nT*4);
  size_t o_tileoff  = alloc((size_t)nT*4);

  if (off > ws_size) {
    TopoAggregator_33217277067466_kernel<<<2048, 256, 0, stream>>>(
        (float*)d_out, out_size, 100.0f);
    return;
  }

  char* w = (char*)d_ws;
  float* h        = (float*)(w + o_h);
  u16*   xl       = (u16*)(w + o_xl);
  u16*   xr       = (u16*)(w + o_xr);
  u32*   rel_s    = (u32*)(w + o_rels);
  float* relmean  = (float*)(w + o_relmean);
  int*   counts   = (int*)(w + o_counts);
  int*   rowstart = (int*)(w + o_rowstart);
  int*   cursor   = (int*)(w + o_cursor);
  int*   adj_src  = (int*)(w + o_adjsrc);
  int*   tilesum  = (int*)(w + o_tilesum);
  int*   tileoff  = (int*)(w + o_tileoff);

  k_zero<<<(N+255)/256, 256, 0, stream>>>(counts, relmean, N);
  k_relmean<<<64, 256, 0, stream>>>(relation, relmean, E);
  k_count<<<(E+255)/256, 256, 0, stream>>>(edges, counts, E, N);
  k_scan_a<<<nT, 256, 0, stream>>>(counts, tilesum, N);
  k_scan_b<<<1, 1024, 0, stream>>>(tilesum, tileoff, nT);
  k_scan_c<<<nT, 1024, 0, stream>>>(counts, tileoff, rowstart, cursor, N);
  k_scatter<<<(E+255)/256, 256, 0, stream>>>(edges, relation, cursor, adj_src, rel_s, E, N);

  k_embed<<<(N+3)/4, 256, 0, stream>>>(nodes, time_emb, type_emb, biway_emb, islink_emb,
                                       proj_w, proj_b, h, N);

  for(int l=0; l<2; l++){
    k_xlr<<<2048, 256, 0, stream>>>(h,
        lin_l_w + (size_t)l*HHID*64, lin_l_b + (size_t)l*HHID,
        lin_r_w + (size_t)l*HHID*64, lin_r_b + (size_t)l*HHID,
        xl, xr, N, nTiles);
    k_fused<<<4096, 256, 0, stream>>>(rowstart, adj_src, rel_s, relmean,
        lin_e_w + (size_t)l*HHID*16, att + (size_t)l*HEADS*64,
        xl, xr, gat_b + (size_t)l*64,
        h, N,
        (l==1) ? (float*)d_out : (float*)nullptr);
  }
  k_marker<<<1, 64, 0, stream>>>(rowstart, h, (float*)d_out, N, E);
}

// Round 19
// 965.663 us; speedup vs baseline: 1.2327x; 1.2327x over previous
//
#include <hip/hip_runtime.h>

typedef unsigned short u16;
typedef unsigned int u32;

__device__ __forceinline__ float bf2f(u16 u){ union{u32 i; float f;} v; v.i=((u32)u)<<16; return v.f; }
__device__ __forceinline__ float bflo(u32 p){ union{u32 i; float f;} v; v.i=p<<16; return v.f; }
__device__ __forceinline__ float bfhi(u32 p){ union{u32 i; float f;} v; v.i=p&0xffff0000u; return v.f; }
__device__ __forceinline__ u16 f2bf(float x){ union{float f; u32 i;} v; v.f=x; u32 b=v.i;
  return (u16)((b + 0x7fffu + ((b>>16)&1u))>>16); }
__device__ __forceinline__ u32 pk2(float a, float b){ return ((u32)f2bf(b)<<16) | (u32)f2bf(a); }

#define HEADS 4
#define HHID 256   // HEADS*HID
#define NT 16      // nodes per tile in k_xlr

// ---- fill d_out with a float value (diagnostic only) ----
__global__ void TopoAggregator_33217277067466_kernel(float* __restrict__ out, int n, float val){
  for(int i = blockIdx.x*blockDim.x + threadIdx.x; i < n; i += gridDim.x*blockDim.x)
    out[i] = val;
}

// ---- post-hoc invariant marker: touches d_out ONLY on failure ----
__global__ void k_marker(const int* __restrict__ rowstart, const float* __restrict__ h,
                         float* __restrict__ out, int N, int E){
  if(threadIdx.x!=0 || blockIdx.x!=0) return;
  float M = 0.f;
  if(rowstart[N] != E) M = 400.f;
  else {
    int allz = 1;
    for(int i=0;i<128;i++) if(h[i]!=0.f){ allz=0; break; }
    if(allz) M = 500.f;
  }
  if(M != 0.f) out[0] = M;
}

// ---- zero counts[N] and relmean[16] ----
__global__ void k_zero(int* __restrict__ counts, float* __restrict__ relmean, int N){
  int i = blockIdx.x*blockDim.x + threadIdx.x;
  if(i < N) counts[i] = 0;
  if(i < 16) relmean[i] = 0.f;
}

// ---- relation mean over E rows of 16 (f32) ----
__global__ void k_relmean(const float* __restrict__ rel, float* __restrict__ relmean, int E){
  __shared__ float red[256][16];
  float s[16];
#pragma unroll
  for(int j=0;j<16;j++) s[j]=0.f;
  for(int r = blockIdx.x*blockDim.x + threadIdx.x; r < E; r += gridDim.x*blockDim.x){
    const float4* p = (const float4*)(rel + (size_t)r*16);
    float4 a=p[0], b=p[1], c=p[2], d=p[3];
    s[0]+=a.x; s[1]+=a.y; s[2]+=a.z; s[3]+=a.w;
    s[4]+=b.x; s[5]+=b.y; s[6]+=b.z; s[7]+=b.w;
    s[8]+=c.x; s[9]+=c.y; s[10]+=c.z; s[11]+=c.w;
    s[12]+=d.x; s[13]+=d.y; s[14]+=d.z; s[15]+=d.w;
  }
  int tid = threadIdx.x;
#pragma unroll
  for(int j=0;j<16;j++) red[tid][j]=s[j];
  __syncthreads();
  for(int off=128; off>0; off>>=1){
    if(tid<off){
#pragma unroll
      for(int j=0;j<16;j++) red[tid][j]+=red[tid+off][j];
    }
    __syncthreads();
  }
  if(tid<16) atomicAdd(relmean+tid, red[0][tid]*(1.0f/(float)E));
}

// ---- CSR build over REAL edges only (self-loops handled analytically) ----
__global__ void k_count(const int* __restrict__ edges, int* __restrict__ counts, int E, int N){
  int e = blockIdx.x*blockDim.x + threadIdx.x;
  if(e>=E) return;
  int d = edges[E+e];
  if(d<0) d=0; if(d>=N) d=N-1;
  atomicAdd(counts+d, 1);
}

// ---- 3-phase parallel exclusive scan over counts[N] ----
#define STILE 1024
__global__ void k_scan_a(const int* __restrict__ counts, int* __restrict__ tilesum, int N){
  __shared__ int red[256];
  int base = blockIdx.x*STILE;
  int tid = threadIdx.x;
  int s = 0;
  for(int i=tid; i<STILE; i+=256){
    int idx = base + i;
    s += (idx < N) ? counts[idx] : 0;
  }
  red[tid] = s;
  __syncthreads();
  for(int off=128; off>0; off>>=1){
    if(tid<off) red[tid] += red[tid+off];
    __syncthreads();
  }
  if(tid==0) tilesum[blockIdx.x] = red[0];
}

__global__ void k_scan_b(const int* __restrict__ tilesum, int* __restrict__ tileoff, int nT){
  __shared__ int buf[1024];
  int tid = threadIdx.x;
  buf[tid] = (tid < nT) ? tilesum[tid] : 0;
  __syncthreads();
  for(int off=1; off<1024; off<<=1){
    int v = (tid>=off) ? buf[tid-off] : 0;
    __syncthreads();
    buf[tid] += v;
    __syncthreads();
  }
  if(tid < nT) tileoff[tid] = (tid==0) ? 0 : buf[tid-1];
}

__global__ void k_scan_c(const int* __restrict__ counts, const int* __restrict__ tileoff,
                         int* __restrict__ rowstart, int* __restrict__ cursor, int N){
  __shared__ int buf[STILE];
  int base = blockIdx.x*STILE;
  int tid = threadIdx.x;
  int idx = base + tid;
  int c = (idx < N) ? counts[idx] : 0;
  buf[tid] = c;
  __syncthreads();
  for(int off=1; off<1024; off<<=1){
    int v = (tid>=off) ? buf[tid-off] : 0;
    __syncthreads();
    buf[tid] += v;
    __syncthreads();
  }
  int excl = buf[tid] - c + tileoff[blockIdx.x];
  if(idx < N){ rowstart[idx]=excl; cursor[idx]=excl; }
  if(idx == N-1) rowstart[N] = excl + c;
}

// scatter src AND the rel row (packed bf16, CSR order)
__global__ void k_scatter(const int* __restrict__ edges, const float* __restrict__ relation,
                          int* __restrict__ cursor,
                          int* __restrict__ adj_src, u32* __restrict__ rel_s, int E, int N){
  int e = blockIdx.x*blockDim.x + threadIdx.x;
  if(e>=E) return;
  int s = edges[e], d = edges[E+e];
  if(d<0) d=0; if(d>=N) d=N-1;
  int pos = atomicAdd(cursor+d, 1);
  adj_src[pos]=s;
  const float4* rp = (const float4*)(relation + (size_t)e*16);
  float4 q0=rp[0], q1=rp[1], q2=rp[2], q3=rp[3];
  uint4* dst = (uint4*)(rel_s + (size_t)pos*8);
  dst[0] = make_uint4(pk2(q0.x,q0.y), pk2(q0.z,q0.w), pk2(q1.x,q1.y), pk2(q1.z,q1.w));
  dst[1] = make_uint4(pk2(q2.x,q2.y), pk2(q2.z,q2.w), pk2(q3.x,q3.y), pk2(q3.z,q3.w));
}

// ---- embedding + input projection: h[N][64] (f32) ----
__global__ void k_embed(const float* __restrict__ nodes,
                        const float* __restrict__ time_emb, const float* __restrict__ type_emb,
                        const float* __restrict__ biway_emb, const float* __restrict__ islink_emb,
                        const float* __restrict__ projw, const float* __restrict__ projb,
                        float* __restrict__ h, int N){
  __shared__ float W[64][65];
  __shared__ float h0[4][64];
  int tid = threadIdx.x;
  for(int i=tid; i<64*64; i+=256) W[i>>6][i&63] = projw[i];
  __syncthreads();
  int wave = tid>>6, lane = tid&63;
  int node = blockIdx.x*4 + wave;
  if(node<N){
    const float* nr = nodes + (size_t)node*20;
    float v; int c = lane;
    if(c<16){
      int t=(int)nr[0]; t = t<0?0:(t>287?287:t);
      v = time_emb[t*16+c];
    } else if(c<32){
      int ty=(int)nr[1]; ty = ty<0?0:(ty>15?15:ty);
      v = type_emb[ty*16+(c-16)];
    } else if(c<40){
      int bw=(int)nr[2]; bw = bw<0?0:(bw>1?1:bw);
      v = biway_emb[bw*8+(c-32)];
    } else if(c<48){
      int il=(int)nr[3]; il = il<0?0:(il>1?1:il);
      v = islink_emb[il*8+(c-40)];
    } else {
      v = nr[4 + (c-48)];
    }
    h0[wave][lane]=v;
  }
  __syncthreads();
  if(node<N){
    float acc = projb[lane];
#pragma unroll
    for(int k=0;k<64;k++) acc += W[lane][k]*h0[wave][k];
    h[(size_t)node*64+lane]=acc;
  }
}

// ---- xl/xr = h @ {wl,wr}.T + {bl,br}, stored bf16. 16 nodes/block (r17 version) ----
__global__ void k_xlr(const float* __restrict__ h,
                      const float* __restrict__ wl, const float* __restrict__ bl,
                      const float* __restrict__ wr, const float* __restrict__ br,
                      u16* __restrict__ xl, u16* __restrict__ xr, int N){
  __shared__ float hs[NT*64];
  int tid = threadIdx.x;
  int base = blockIdx.x*NT;
  int nvalid = N - base; if(nvalid > NT) nvalid = NT;
  if(nvalid == NT){
    *(float4*)(hs + tid*4) = *(const float4*)(h + (size_t)base*64 + tid*4);
  } else {
    for(int i=tid; i<NT*64; i+=256) hs[i] = (i < nvalid*64) ? h[(size_t)base*64+i] : 0.f;
  }
  __syncthreads();
  int o = tid;   // output channel 0..255
  const float4* wl4 = (const float4*)(wl + (size_t)o*64);
  const float4* wr4 = (const float4*)(wr + (size_t)o*64);
  float blv = bl[o], brv = br[o];
  float accl[NT], accr[NT];
#pragma unroll
  for(int n=0;n<NT;n++){ accl[n]=blv; accr[n]=brv; }
  for(int kk=0; kk<16; kk++){
    float4 a = wl4[kk];
    float4 b = wr4[kk];
#pragma unroll
    for(int n=0;n<NT;n++){
      float4 hv = *(const float4*)(hs + n*64 + kk*4);
      accl[n] += a.x*hv.x + a.y*hv.y + a.z*hv.z + a.w*hv.w;
      accr[n] += b.x*hv.x + b.y*hv.y + b.z*hv.z + b.w*hv.w;
    }
  }
  for(int n=0;n<nvalid;n++){
    xl[(size_t)(base+n)*HHID + o] = f2bf(accl[n]);
    xr[(size_t)(base+n)*HHID + o] = f2bf(accr[n]);
  }
}

// ---- fused per-node: PAIRED edge processing sharing weT LDS reads ----
__global__ void __launch_bounds__(256)
k_fused(const int* __restrict__ rowstart, const int* __restrict__ adj_src,
        const u32* __restrict__ rel_s, const float* __restrict__ relmean,
        const float* __restrict__ we, const float* __restrict__ att,
        const u16* __restrict__ xl, const u16* __restrict__ xr,
        const float* __restrict__ gat_b,
        float* __restrict__ h, int N, float* __restrict__ outp){
  __shared__ float weT[16*256];   // [k][ch]
  {
    int tid = threadIdx.x;
    for(int i=tid; i<16*256; i+=256){
      int k = i >> 8, ch = i & 255;
      weT[k*256 + ch] = we[(size_t)ch*16 + k];
    }
  }
  __syncthreads();
  const int lane = threadIdx.x & 63;
  const int sub = lane & 15;
  const int wid = (blockIdx.x*blockDim.x + threadIdx.x) >> 6;
  const int nw  = (gridDim.x*blockDim.x) >> 6;
  const float4* wT4 = (const float4*)weT;   // index: k*64 + lane

  const float4 at4 = *(const float4*)(att + lane*4);

  // self-loop ep (per-wave constant)
  float es0=0.f, es1=0.f, es2=0.f, es3=0.f;
#pragma unroll
  for(int k=0;k<16;k++){
    float rmk = relmean[k];
    float4 w4 = wT4[k*64 + lane];
    es0 += rmk*w4.x; es1 += rmk*w4.y; es2 += rmk*w4.z; es3 += rmk*w4.w;
  }

  for(int node = wid; node < N; node += nw){
    const int lo = rowstart[node], hi = rowstart[node+1];
    uint2 pb = *(const uint2*)(xr + (size_t)node*HHID + lane*4);
    float bv0=bflo(pb.x), bv1=bfhi(pb.x), bv2=bflo(pb.y), bv3=bfhi(pb.y);

    // self-loop initializes online softmax
    float m, den, a0, a1, a2, a3;
    {
      uint2 ps = *(const uint2*)(xl + (size_t)node*HHID + lane*4);
      float sv0=bflo(ps.x), sv1=bfhi(ps.x), sv2=bflo(ps.y), sv3=bfhi(ps.y);
      float c = 0.f;
      {
        float mm;
        mm = sv0 + bv0 + es0; mm = (mm>0.f)?mm:0.2f*mm; c += mm*at4.x;
        mm = sv1 + bv1 + es1; mm = (mm>0.f)?mm:0.2f*mm; c += mm*at4.y;
        mm = sv2 + bv2 + es2; mm = (mm>0.f)?mm:0.2f*mm; c += mm*at4.z;
        mm = sv3 + bv3 + es3; mm = (mm>0.f)?mm:0.2f*mm; c += mm*at4.w;
      }
      c += __shfl_xor(c, 1);
      c += __shfl_xor(c, 2);
      c += __shfl_xor(c, 4);
      c += __shfl_xor(c, 8);
      m = c; den = 1.f;
      a0 = sv0; a1 = sv1; a2 = sv2; a3 = sv3;
    }

    if(lo < hi){
      // index prefetch for pair0 and pair1
      int sA1 = (lo+2<hi) ? adj_src[lo+2] : 0;
      int sB1 = (lo+3<hi) ? adj_src[lo+3] : 0;
      // data for pair0
      uint4 rA0c, rA1c; uint2 paAc;
      {
        int sv = adj_src[lo]; if(sv<0) sv=0; if(sv>=N) sv=N-1;
        const uint4* rp = (const uint4*)(rel_s + (size_t)lo*8);
        rA0c = rp[0]; rA1c = rp[1];
        paAc = *(const uint2*)(xl + (size_t)sv*HHID + lane*4);
      }
      uint4 rB0c = make_uint4(0,0,0,0), rB1c = rB0c; uint2 paBc = make_uint2(0u,0u);
      if(lo+1 < hi){
        int sv = adj_src[lo+1]; if(sv<0) sv=0; if(sv>=N) sv=N-1;
        const uint4* rp = (const uint4*)(rel_s + (size_t)(lo+1)*8);
        rB0c = rp[0]; rB1c = rp[1];
        paBc = *(const uint2*)(xl + (size_t)sv*HHID + lane*4);
      }

      for(int p=lo; p<hi; p+=2){
        // stage 1: data prefetch for pair p+2 (indices resident)
        uint4 rA0n = make_uint4(0,0,0,0), rA1n = rA0n, rB0n = rA0n, rB1n = rA0n;
        uint2 paAn = make_uint2(0u,0u), paBn = paAn;
        if(p+2 < hi){
          int sv = sA1; if(sv<0) sv=0; if(sv>=N) sv=N-1;
          const uint4* rp = (const uint4*)(rel_s + (size_t)(p+2)*8);
          rA0n = rp[0]; rA1n = rp[1];
          paAn = *(const uint2*)(xl + (size_t)sv*HHID + lane*4);
          if(p+3 < hi){
            int sv2 = sB1; if(sv2<0) sv2=0; if(sv2>=N) sv2=N-1;
            const uint4* rp2 = (const uint4*)(rel_s + (size_t)(p+3)*8);
            rB0n = rp2[0]; rB1n = rp2[1];
            paBn = *(const uint2*)(xl + (size_t)sv2*HHID + lane*4);
          }
        }
        // stage 2: index prefetch for pair p+4
        int sA2 = (p+4<hi) ? adj_src[p+4] : 0;
        int sB2 = (p+5<hi) ? adj_src[p+5] : 0;

        // stage 3: compute edges p and p+1 sharing weT reads
        float eA0=0.f,eA1=0.f,eA2=0.f,eA3=0.f, eB0=0.f,eB1=0.f,eB2=0.f,eB3=0.f;
#define EPW2(WA, WB, KB) { \
        float al=bflo(WA), ah=bfhi(WA), bl_=bflo(WB), bh_=bfhi(WB); \
        float4 wa = wT4[(KB)*64 + lane]; \
        float4 wb = wT4[(KB+1)*64 + lane]; \
        eA0 += al*wa.x + ah*wb.x;  eB0 += bl_*wa.x + bh_*wb.x; \
        eA1 += al*wa.y + ah*wb.y;  eB1 += bl_*wa.y + bh_*wb.y; \
        eA2 += al*wa.z + ah*wb.z;  eB2 += bl_*wa.z + bh_*wb.z; \
        eA3 += al*wa.w + ah*wb.w;  eB3 += bl_*wa.w + bh_*wb.w; }
        EPW2(rA0c.x, rB0c.x, 0)  EPW2(rA0c.y, rB0c.y, 2)
        EPW2(rA0c.z, rB0c.z, 4)  EPW2(rA0c.w, rB0c.w, 6)
        EPW2(rA1c.x, rB1c.x, 8)  EPW2(rA1c.y, rB1c.y,10)
        EPW2(rA1c.z, rB1c.z,12)  EPW2(rA1c.w, rB1c.w,14)
#undef EPW2

        float avA0=bflo(paAc.x), avA1=bfhi(paAc.x), avA2=bflo(paAc.y), avA3=bfhi(paAc.y);
        float avB0=bflo(paBc.x), avB1=bfhi(paBc.x), avB2=bflo(paBc.y), avB3=bfhi(paBc.y);
        float cA = 0.f, cB = 0.f;
        {
          float mm;
          mm = avA0 + bv0 + eA0; mm=(mm>0.f)?mm:0.2f*mm; cA += mm*at4.x;
          mm = avA1 + bv1 + eA1; mm=(mm>0.f)?mm:0.2f*mm; cA += mm*at4.y;
          mm = avA2 + bv2 + eA2; mm=(mm>0.f)?mm:0.2f*mm; cA += mm*at4.z;
          mm = avA3 + bv3 + eA3; mm=(mm>0.f)?mm:0.2f*mm; cA += mm*at4.w;
          mm = avB0 + bv0 + eB0; mm=(mm>0.f)?mm:0.2f*mm; cB += mm*at4.x;
          mm = avB1 + bv1 + eB1; mm=(mm>0.f)?mm:0.2f*mm; cB += mm*at4.y;
          mm = avB2 + bv2 + eB2; mm=(mm>0.f)?mm:0.2f*mm; cB += mm*at4.z;
          mm = avB3 + bv3 + eB3; mm=(mm>0.f)?mm:0.2f*mm; cB += mm*at4.w;
        }
        cA += __shfl_xor(cA, 1); cB += __shfl_xor(cB, 1);
        cA += __shfl_xor(cA, 2); cB += __shfl_xor(cB, 2);
        cA += __shfl_xor(cA, 4); cB += __shfl_xor(cB, 4);
        cA += __shfl_xor(cA, 8); cB += __shfl_xor(cB, 8);
        if(p+1 >= hi) cB = -1e30f;   // invalid tail edge -> weight 0

        // online softmax update, edge A then edge B
        if(cA > m){
          float sc = __expf(m - cA);
          den *= sc; a0 *= sc; a1 *= sc; a2 *= sc; a3 *= sc;
          m = cA;
        }
        float wA = __expf(cA - m);
        den += wA;
        a0 += wA*avA0; a1 += wA*avA1; a2 += wA*avA2; a3 += wA*avA3;

        if(cB > m){
          float sc = __expf(m - cB);
          den *= sc; a0 *= sc; a1 *= sc; a2 *= sc; a3 *= sc;
          m = cB;
        }
        float wB = __expf(cB - m);
        den += wB;
        a0 += wB*avB0; a1 += wB*avB1; a2 += wB*avB2; a3 += wB*avB3;

        // rotate pipeline
        rA0c = rA0n; rA1c = rA1n; rB0c = rB0n; rB1c = rB1n;
        paAc = paAn; paBc = paBn;
        sA1 = sA2; sB1 = sB2;
      }
    }

    float inv = 1.0f/den;
    float v0=a0*inv, v1=a1*inv, v2=a2*inv, v3=a3*inv;
    v0 += __shfl_xor(v0,16); v0 += __shfl_xor(v0,32);
    v1 += __shfl_xor(v1,16); v1 += __shfl_xor(v1,32);
    v2 += __shfl_xor(v2,16); v2 += __shfl_xor(v2,32);
    v3 += __shfl_xor(v3,16); v3 += __shfl_xor(v3,32);
    if(lane < 16){
      int cb = sub*4;
      float4 hv = *(const float4*)(h + (size_t)node*64 + cb);
      const float4 gb = *(const float4*)(gat_b + cb);
      float o0 = fmaxf(0.25f*v0 + gb.x + hv.x, 0.f);
      float o1 = fmaxf(0.25f*v1 + gb.y + hv.y, 0.f);
      float o2 = fmaxf(0.25f*v2 + gb.z + hv.z, 0.f);
      float o3 = fmaxf(0.25f*v3 + gb.w + hv.w, 0.f);
      *(float4*)(h + (size_t)node*64 + cb) = make_float4(o0,o1,o2,o3);
      if(outp) *(float4*)(outp + (size_t)node*64 + cb) = make_float4(o0,o1,o2,o3);
    }
  }
}

extern "C" void kernel_launch(void* const* d_in, const int* in_sizes, int n_in,
                              void* d_out, int out_size, void* d_ws, size_t ws_size,
                              hipStream_t stream) {
  const float* nodes     = (const float*)d_in[0];
  const int*   edges     = (const int*)d_in[1];
  const float* relation  = (const float*)d_in[2];
  const float* time_emb  = (const float*)d_in[3];
  const float* type_emb  = (const float*)d_in[4];
  const float* biway_emb = (const float*)d_in[5];
  const float* islink_emb= (const float*)d_in[6];
  const float* proj_w    = (const float*)d_in[7];
  const float* proj_b    = (const float*)d_in[8];
  const float* lin_l_w   = (const float*)d_in[9];
  const float* lin_l_b   = (const float*)d_in[10];
  const float* lin_r_w   = (const float*)d_in[11];
  const float* lin_r_b   = (const float*)d_in[12];
  const float* lin_e_w   = (const float*)d_in[13];
  const float* att       = (const float*)d_in[14];
  const float* gat_b     = (const float*)d_in[15];

  const int N  = in_sizes[0] / 20;
  const int E  = in_sizes[1] / 2;
  const int nT = (N + STILE - 1) / STILE;

  size_t off = 0;
  auto alloc = [&](size_t bytes)->size_t {
    size_t p = off;
    off += ((bytes + 255) / 256) * 256;
    return p;
  };
  size_t o_h        = alloc((size_t)N*64*4);        // f32
  size_t o_xl       = alloc((size_t)N*HHID*2);      // bf16
  size_t o_xr       = alloc((size_t)N*HHID*2);      // bf16
  size_t o_rels     = alloc((size_t)E*32);          // bf16 rel rows, CSR order
  size_t o_relmean  = alloc(64*4);
  size_t o_counts   = alloc((size_t)N*4);
  size_t o_rowstart = alloc((size_t)(N+1)*4);
  size_t o_cursor   = alloc((size_t)(N+1)*4);
  size_t o_adjsrc   = alloc((size_t)E*4);
  size_t o_tilesum  = alloc((size_t)nT*4);
  size_t o_tileoff  = alloc((size_t)nT*4);

  if (off > ws_size) {
    TopoAggregator_33217277067466_kernel<<<2048, 256, 0, stream>>>(
        (float*)d_out, out_size, 100.0f);
    return;
  }

  char* w = (char*)d_ws;
  float* h        = (float*)(w + o_h);
  u16*   xl       = (u16*)(w + o_xl);
  u16*   xr       = (u16*)(w + o_xr);
  u32*   rel_s    = (u32*)(w + o_rels);
  float* relmean  = (float*)(w + o_relmean);
  int*   counts   = (int*)(w + o_counts);
  int*   rowstart = (int*)(w + o_rowstart);
  int*   cursor   = (int*)(w + o_cursor);
  int*   adj_src  = (int*)(w + o_adjsrc);
  int*   tilesum  = (int*)(w + o_tilesum);
  int*   tileoff  = (int*)(w + o_tileoff);

  k_zero<<<(N+255)/256, 256, 0, stream>>>(counts, relmean, N);
  k_relmean<<<64, 256, 0, stream>>>(relation, relmean, E);
  k_count<<<(E+255)/256, 256, 0, stream>>>(edges, counts, E, N);
  k_scan_a<<<nT, 256, 0, stream>>>(counts, tilesum, N);
  k_scan_b<<<1, 1024, 0, stream>>>(tilesum, tileoff, nT);
  k_scan_c<<<nT, 1024, 0, stream>>>(counts, tileoff, rowstart, cursor, N);
  k_scatter<<<(E+255)/256, 256, 0, stream>>>(edges, relation, cursor, adj_src, rel_s, E, N);

  k_embed<<<(N+3)/4, 256, 0, stream>>>(nodes, time_emb, type_emb, biway_emb, islink_emb,
                                       proj_w, proj_b, h, N);

  for(int l=0; l<2; l++){
    k_xlr<<<(N+NT-1)/NT, 256, 0, stream>>>(h,
        lin_l_w + (size_t)l*HHID*64, lin_l_b + (size_t)l*HHID,
        lin_r_w + (size_t)l*HHID*64, lin_r_b + (size_t)l*HHID,
        xl, xr, N);
    k_fused<<<4096, 256, 0, stream>>>(rowstart, adj_src, rel_s, relmean,
        lin_e_w + (size_t)l*HHID*16, att + (size_t)l*HEADS*64,
        xl, xr, gat_b + (size_t)l*64,
        h, N,
        (l==1) ? (float*)d_out : (float*)nullptr);
  }
  k_marker<<<1, 64, 0, stream>>>(rowstart, h, (float*)d_out, N, E);
}

// Round 20
// 887.145 us; speedup vs baseline: 1.3418x; 1.0885x over previous
//
#include <hip/hip_runtime.h>

typedef unsigned short u16;
typedef unsigned int u32;

__device__ __forceinline__ float bf2f(u16 u){ union{u32 i; float f;} v; v.i=((u32)u)<<16; return v.f; }
__device__ __forceinline__ float bflo(u32 p){ union{u32 i; float f;} v; v.i=p<<16; return v.f; }
__device__ __forceinline__ float bfhi(u32 p){ union{u32 i; float f;} v; v.i=p&0xffff0000u; return v.f; }
__device__ __forceinline__ u16 f2bf(float x){ union{float f; u32 i;} v; v.f=x; u32 b=v.i;
  return (u16)((b + 0x7fffu + ((b>>16)&1u))>>16); }
__device__ __forceinline__ u32 pk2(float a, float b){ return ((u32)f2bf(b)<<16) | (u32)f2bf(a); }

#define HEADS 4
#define HHID 256   // HEADS*HID
#define NT 16      // nodes per tile in k_xlr

// ---- fill d_out with a float value (diagnostic only) ----
__global__ void TopoAggregator_33217277067466_kernel(float* __restrict__ out, int n, float val){
  for(int i = blockIdx.x*blockDim.x + threadIdx.x; i < n; i += gridDim.x*blockDim.x)
    out[i] = val;
}

// ---- post-hoc invariant marker: touches d_out ONLY on failure ----
__global__ void k_marker(const int* __restrict__ rowstart, const float* __restrict__ h,
                         float* __restrict__ out, int N, int E){
  if(threadIdx.x!=0 || blockIdx.x!=0) return;
  float M = 0.f;
  if(rowstart[N] != E) M = 400.f;
  else {
    int allz = 1;
    for(int i=0;i<128;i++) if(h[i]!=0.f){ allz=0; break; }
    if(allz) M = 500.f;
  }
  if(M != 0.f) out[0] = M;
}

// ---- relation mean over E rows of 16 (f32) ----
__global__ void k_relmean(const float* __restrict__ rel, float* __restrict__ relmean, int E){
  __shared__ float red[256][16];
  float s[16];
#pragma unroll
  for(int j=0;j<16;j++) s[j]=0.f;
  for(int r = blockIdx.x*blockDim.x + threadIdx.x; r < E; r += gridDim.x*blockDim.x){
    const float4* p = (const float4*)(rel + (size_t)r*16);
    float4 a=p[0], b=p[1], c=p[2], d=p[3];
    s[0]+=a.x; s[1]+=a.y; s[2]+=a.z; s[3]+=a.w;
    s[4]+=b.x; s[5]+=b.y; s[6]+=b.z; s[7]+=b.w;
    s[8]+=c.x; s[9]+=c.y; s[10]+=c.z; s[11]+=c.w;
    s[12]+=d.x; s[13]+=d.y; s[14]+=d.z; s[15]+=d.w;
  }
  int tid = threadIdx.x;
#pragma unroll
  for(int j=0;j<16;j++) red[tid][j]=s[j];
  __syncthreads();
  for(int off=128; off>0; off>>=1){
    if(tid<off){
#pragma unroll
      for(int j=0;j<16;j++) red[tid][j]+=red[tid+off][j];
    }
    __syncthreads();
  }
  if(tid<16) atomicAdd(relmean+tid, red[0][tid]*(1.0f/(float)E));
}

// ---- CSR build over REAL edges only (self-loops handled analytically) ----
__global__ void k_count(const int* __restrict__ edges, int* __restrict__ counts, int E, int N){
  int e = blockIdx.x*blockDim.x + threadIdx.x;
  if(e>=E) return;
  int d = edges[E+e];
  if(d<0) d=0; if(d>=N) d=N-1;
  atomicAdd(counts+d, 1);
}

// ---- 3-phase parallel exclusive scan over counts[N] ----
#define STILE 1024
__global__ void k_scan_a(const int* __restrict__ counts, int* __restrict__ tilesum, int N){
  __shared__ int red[256];
  int base = blockIdx.x*STILE;
  int tid = threadIdx.x;
  int s = 0;
  for(int i=tid; i<STILE; i+=256){
    int idx = base + i;
    s += (idx < N) ? counts[idx] : 0;
  }
  red[tid] = s;
  __syncthreads();
  for(int off=128; off>0; off>>=1){
    if(tid<off) red[tid] += red[tid+off];
    __syncthreads();
  }
  if(tid==0) tilesum[blockIdx.x] = red[0];
}

__global__ void k_scan_b(const int* __restrict__ tilesum, int* __restrict__ tileoff, int nT){
  __shared__ int buf[1024];
  int tid = threadIdx.x;
  buf[tid] = (tid < nT) ? tilesum[tid] : 0;
  __syncthreads();
  for(int off=1; off<1024; off<<=1){
    int v = (tid>=off) ? buf[tid-off] : 0;
    __syncthreads();
    buf[tid] += v;
    __syncthreads();
  }
  if(tid < nT) tileoff[tid] = (tid==0) ? 0 : buf[tid-1];
}

__global__ void k_scan_c(const int* __restrict__ counts, const int* __restrict__ tileoff,
                         int* __restrict__ rowstart, int* __restrict__ cursor, int N){
  __shared__ int buf[STILE];
  int base = blockIdx.x*STILE;
  int tid = threadIdx.x;
  int idx = base + tid;
  int c = (idx < N) ? counts[idx] : 0;
  buf[tid] = c;
  __syncthreads();
  for(int off=1; off<1024; off<<=1){
    int v = (tid>=off) ? buf[tid-off] : 0;
    __syncthreads();
    buf[tid] += v;
    __syncthreads();
  }
  int excl = buf[tid] - c + tileoff[blockIdx.x];
  if(idx < N){ rowstart[idx]=excl; cursor[idx]=excl; }
  if(idx == N-1) rowstart[N] = excl + c;
}

// scatter src AND the rel row (packed bf16, CSR order)
__global__ void k_scatter(const int* __restrict__ edges, const float* __restrict__ relation,
                          int* __restrict__ cursor,
                          int* __restrict__ adj_src, u32* __restrict__ rel_s, int E, int N){
  int e = blockIdx.x*blockDim.x + threadIdx.x;
  if(e>=E) return;
  int s = edges[e], d = edges[E+e];
  if(d<0) d=0; if(d>=N) d=N-1;
  int pos = atomicAdd(cursor+d, 1);
  adj_src[pos]=s;
  const float4* rp = (const float4*)(relation + (size_t)e*16);
  float4 q0=rp[0], q1=rp[1], q2=rp[2], q3=rp[3];
  uint4* dst = (uint4*)(rel_s + (size_t)pos*8);
  dst[0] = make_uint4(pk2(q0.x,q0.y), pk2(q0.z,q0.w), pk2(q1.x,q1.y), pk2(q1.z,q1.w));
  dst[1] = make_uint4(pk2(q2.x,q2.y), pk2(q2.z,q2.w), pk2(q3.x,q3.y), pk2(q3.z,q3.w));
}

// ---- embedding + input projection: h[N][64] (f32) ----
__global__ void k_embed(const float* __restrict__ nodes,
                        const float* __restrict__ time_emb, const float* __restrict__ type_emb,
                        const float* __restrict__ biway_emb, const float* __restrict__ islink_emb,
                        const float* __restrict__ projw, const float* __restrict__ projb,
                        float* __restrict__ h, int N){
  __shared__ float W[64][65];
  __shared__ float h0[4][64];
  int tid = threadIdx.x;
  for(int i=tid; i<64*64; i+=256) W[i>>6][i&63] = projw[i];
  __syncthreads();
  int wave = tid>>6, lane = tid&63;
  int node = blockIdx.x*4 + wave;
  if(node<N){
    const float* nr = nodes + (size_t)node*20;
    float v; int c = lane;
    if(c<16){
      int t=(int)nr[0]; t = t<0?0:(t>287?287:t);
      v = time_emb[t*16+c];
    } else if(c<32){
      int ty=(int)nr[1]; ty = ty<0?0:(ty>15?15:ty);
      v = type_emb[ty*16+(c-16)];
    } else if(c<40){
      int bw=(int)nr[2]; bw = bw<0?0:(bw>1?1:bw);
      v = biway_emb[bw*8+(c-32)];
    } else if(c<48){
      int il=(int)nr[3]; il = il<0?0:(il>1?1:il);
      v = islink_emb[il*8+(c-40)];
    } else {
      v = nr[4 + (c-48)];
    }
    h0[wave][lane]=v;
  }
  __syncthreads();
  if(node<N){
    float acc = projb[lane];
#pragma unroll
    for(int k=0;k<64;k++) acc += W[lane][k]*h0[wave][k];
    h[(size_t)node*64+lane]=acc;
  }
}

// ---- xl/xr = h @ {wl,wr}.T + {bl,br}, stored bf16. 16 nodes/block (r17 version) ----
__global__ void k_xlr(const float* __restrict__ h,
                      const float* __restrict__ wl, const float* __restrict__ bl,
                      const float* __restrict__ wr, const float* __restrict__ br,
                      u16* __restrict__ xl, u16* __restrict__ xr, int N){
  __shared__ float hs[NT*64];
  int tid = threadIdx.x;
  int base = blockIdx.x*NT;
  int nvalid = N - base; if(nvalid > NT) nvalid = NT;
  if(nvalid == NT){
    *(float4*)(hs + tid*4) = *(const float4*)(h + (size_t)base*64 + tid*4);
  } else {
    for(int i=tid; i<NT*64; i+=256) hs[i] = (i < nvalid*64) ? h[(size_t)base*64+i] : 0.f;
  }
  __syncthreads();
  int o = tid;   // output channel 0..255
  const float4* wl4 = (const float4*)(wl + (size_t)o*64);
  const float4* wr4 = (const float4*)(wr + (size_t)o*64);
  float blv = bl[o], brv = br[o];
  float accl[NT], accr[NT];
#pragma unroll
  for(int n=0;n<NT;n++){ accl[n]=blv; accr[n]=brv; }
  for(int kk=0; kk<16; kk++){
    float4 a = wl4[kk];
    float4 b = wr4[kk];
#pragma unroll
    for(int n=0;n<NT;n++){
      float4 hv = *(const float4*)(hs + n*64 + kk*4);
      accl[n] += a.x*hv.x + a.y*hv.y + a.z*hv.z + a.w*hv.w;
      accr[n] += b.x*hv.x + b.y*hv.y + b.z*hv.z + b.w*hv.w;
    }
  }
  for(int n=0;n<nvalid;n++){
    xl[(size_t)(base+n)*HHID + o] = f2bf(accl[n]);
    xr[(size_t)(base+n)*HHID + o] = f2bf(accr[n]);
  }
}

// ---- fused per-node (r17 unpaired structure): weT in LDS, 1-edge pipeline ----
__global__ void __launch_bounds__(256)
k_fused(const int* __restrict__ rowstart, const int* __restrict__ adj_src,
        const u32* __restrict__ rel_s, const float* __restrict__ relmean,
        const float* __restrict__ we, const float* __restrict__ att,
        const u16* __restrict__ xl, const u16* __restrict__ xr,
        const float* __restrict__ gat_b,
        float* __restrict__ h, int N, float* __restrict__ outp){
  __shared__ float weT[16*256];   // [k][ch]
  {
    int tid = threadIdx.x;
    for(int i=tid; i<16*256; i+=256){
      int k = i >> 8, ch = i & 255;
      weT[k*256 + ch] = we[(size_t)ch*16 + k];
    }
  }
  __syncthreads();
  const int lane = threadIdx.x & 63;
  const int sub = lane & 15;
  const int wid = (blockIdx.x*blockDim.x + threadIdx.x) >> 6;
  const int nw  = (gridDim.x*blockDim.x) >> 6;
  const float4* wT4 = (const float4*)weT;   // index: k*64 + lane

  const float4 at4 = *(const float4*)(att + lane*4);

  // self-loop ep (per-wave constant)
  float es0=0.f, es1=0.f, es2=0.f, es3=0.f;
#pragma unroll
  for(int k=0;k<16;k++){
    float rmk = relmean[k];
    float4 w4 = wT4[k*64 + lane];
    es0 += rmk*w4.x; es1 += rmk*w4.y; es2 += rmk*w4.z; es3 += rmk*w4.w;
  }

  for(int node = wid; node < N; node += nw){
    const int lo = rowstart[node], hi = rowstart[node+1];
    uint2 pb = *(const uint2*)(xr + (size_t)node*HHID + lane*4);
    float bv0=bflo(pb.x), bv1=bfhi(pb.x), bv2=bflo(pb.y), bv3=bfhi(pb.y);

    // self-loop initializes online softmax
    float m, den, a0, a1, a2, a3;
    {
      uint2 ps = *(const uint2*)(xl + (size_t)node*HHID + lane*4);
      float sv0=bflo(ps.x), sv1=bfhi(ps.x), sv2=bflo(ps.y), sv3=bfhi(ps.y);
      float c = 0.f;
      {
        float mm;
        mm = sv0 + bv0 + es0; mm = (mm>0.f)?mm:0.2f*mm; c += mm*at4.x;
        mm = sv1 + bv1 + es1; mm = (mm>0.f)?mm:0.2f*mm; c += mm*at4.y;
        mm = sv2 + bv2 + es2; mm = (mm>0.f)?mm:0.2f*mm; c += mm*at4.z;
        mm = sv3 + bv3 + es3; mm = (mm>0.f)?mm:0.2f*mm; c += mm*at4.w;
      }
      c += __shfl_xor(c, 1);
      c += __shfl_xor(c, 2);
      c += __shfl_xor(c, 4);
      c += __shfl_xor(c, 8);
      m = c; den = 1.f;
      a0 = sv0; a1 = sv1; a2 = sv2; a3 = sv3;
    }

    // pipeline prologue: idx(lo), idx(lo+1), data(lo)
    int svB = 0;
    uint4 rqA0 = make_uint4(0,0,0,0), rqA1 = rqA0;
    uint2 paA = make_uint2(0u,0u);
    if(lo < hi){
      int sv = adj_src[lo];
      const uint4* rp = (const uint4*)(rel_s + (size_t)lo*8);
      rqA0 = rp[0]; rqA1 = rp[1];
      paA = *(const uint2*)(xl + (size_t)sv*HHID + lane*4);
    }
    if(lo+1 < hi) svB = adj_src[lo+1];

    for(int p=lo; p<hi; p++){
      // stage 1: data loads for p+1 (index resident in svB)
      uint4 rqB0 = make_uint4(0,0,0,0), rqB1 = rqB0;
      uint2 paB = make_uint2(0u,0u);
      if(p+1 < hi){
        const uint4* rp = (const uint4*)(rel_s + (size_t)(p+1)*8);
        rqB0 = rp[0]; rqB1 = rp[1];
        paB = *(const uint2*)(xl + (size_t)svB*HHID + lane*4);
      }
      // stage 2: index load for p+2
      int svC = 0;
      if(p+2 < hi) svC = adj_src[p+2];

      // stage 3: compute edge p on resident rqA*/paA (LDS weT + VALU)
      float ep0=0.f, ep1=0.f, ep2=0.f, ep3=0.f;
#define EPW(W, KBASE) { \
        float rlo = bflo(W), rhi = bfhi(W); \
        float4 wa = wT4[(KBASE)*64 + lane]; \
        float4 wb = wT4[(KBASE+1)*64 + lane]; \
        ep0 += rlo*wa.x + rhi*wb.x; \
        ep1 += rlo*wa.y + rhi*wb.y; \
        ep2 += rlo*wa.z + rhi*wb.z; \
        ep3 += rlo*wa.w + rhi*wb.w; }
      EPW(rqA0.x, 0)  EPW(rqA0.y, 2)  EPW(rqA0.z, 4)  EPW(rqA0.w, 6)
      EPW(rqA1.x, 8)  EPW(rqA1.y,10)  EPW(rqA1.z,12)  EPW(rqA1.w,14)
#undef EPW

      float av0=bflo(paA.x), av1=bfhi(paA.x), av2=bflo(paA.y), av3=bfhi(paA.y);
      float c = 0.f;
      {
        float mm;
        mm = av0 + bv0 + ep0; mm = (mm>0.f)?mm:0.2f*mm; c += mm*at4.x;
        mm = av1 + bv1 + ep1; mm = (mm>0.f)?mm:0.2f*mm; c += mm*at4.y;
        mm = av2 + bv2 + ep2; mm = (mm>0.f)?mm:0.2f*mm; c += mm*at4.z;
        mm = av3 + bv3 + ep3; mm = (mm>0.f)?mm:0.2f*mm; c += mm*at4.w;
      }
      c += __shfl_xor(c, 1);
      c += __shfl_xor(c, 2);
      c += __shfl_xor(c, 4);
      c += __shfl_xor(c, 8);

      if(c > m){
        float sc = __expf(m - c);
        den *= sc; a0 *= sc; a1 *= sc; a2 *= sc; a3 *= sc;
        m = c;
      }
      float wgt = __expf(c - m);
      den += wgt;
      a0 += wgt*av0; a1 += wgt*av1; a2 += wgt*av2; a3 += wgt*av3;

      // rotate pipeline
      rqA0 = rqB0; rqA1 = rqB1; paA = paB; svB = svC;
    }

    float inv = 1.0f/den;
    float v0=a0*inv, v1=a1*inv, v2=a2*inv, v3=a3*inv;
    v0 += __shfl_xor(v0,16); v0 += __shfl_xor(v0,32);
    v1 += __shfl_xor(v1,16); v1 += __shfl_xor(v1,32);
    v2 += __shfl_xor(v2,16); v2 += __shfl_xor(v2,32);
    v3 += __shfl_xor(v3,16); v3 += __shfl_xor(v3,32);
    if(lane < 16){
      int cb = sub*4;
      float4 hv = *(const float4*)(h + (size_t)node*64 + cb);
      const float4 gb = *(const float4*)(gat_b + cb);
      float o0 = fmaxf(0.25f*v0 + gb.x + hv.x, 0.f);
      float o1 = fmaxf(0.25f*v1 + gb.y + hv.y, 0.f);
      float o2 = fmaxf(0.25f*v2 + gb.z + hv.z, 0.f);
      float o3 = fmaxf(0.25f*v3 + gb.w + hv.w, 0.f);
      *(float4*)(h + (size_t)node*64 + cb) = make_float4(o0,o1,o2,o3);
      if(outp) *(float4*)(outp + (size_t)node*64 + cb) = make_float4(o0,o1,o2,o3);
    }
  }
}

extern "C" void kernel_launch(void* const* d_in, const int* in_sizes, int n_in,
                              void* d_out, int out_size, void* d_ws, size_t ws_size,
                              hipStream_t stream) {
  const float* nodes     = (const float*)d_in[0];
  const int*   edges     = (const int*)d_in[1];
  const float* relation  = (const float*)d_in[2];
  const float* time_emb  = (const float*)d_in[3];
  const float* type_emb  = (const float*)d_in[4];
  const float* biway_emb = (const float*)d_in[5];
  const float* islink_emb= (const float*)d_in[6];
  const float* proj_w    = (const float*)d_in[7];
  const float* proj_b    = (const float*)d_in[8];
  const float* lin_l_w   = (const float*)d_in[9];
  const float* lin_l_b   = (const float*)d_in[10];
  const float* lin_r_w   = (const float*)d_in[11];
  const float* lin_r_b   = (const float*)d_in[12];
  const float* lin_e_w   = (const float*)d_in[13];
  const float* att       = (const float*)d_in[14];
  const float* gat_b     = (const float*)d_in[15];

  const int N  = in_sizes[0] / 20;
  const int E  = in_sizes[1] / 2;
  const int nT = (N + STILE - 1) / STILE;

  size_t off = 0;
  auto alloc = [&](size_t bytes)->size_t {
    size_t p = off;
    off += ((bytes + 255) / 256) * 256;
    return p;
  };
  size_t o_h        = alloc((size_t)N*64*4);        // f32
  size_t o_xl       = alloc((size_t)N*HHID*2);      // bf16
  size_t o_xr       = alloc((size_t)N*HHID*2);      // bf16
  size_t o_rels     = alloc((size_t)E*32);          // bf16 rel rows, CSR order
  size_t o_relmean  = alloc(64*4);
  size_t o_counts   = alloc((size_t)N*4);
  size_t o_rowstart = alloc((size_t)(N+1)*4);
  size_t o_cursor   = alloc((size_t)(N+1)*4);
  size_t o_adjsrc   = alloc((size_t)E*4);
  size_t o_tilesum  = alloc((size_t)nT*4);
  size_t o_tileoff  = alloc((size_t)nT*4);

  if (off > ws_size) {
    TopoAggregator_33217277067466_kernel<<<2048, 256, 0, stream>>>(
        (float*)d_out, out_size, 100.0f);
    return;
  }

  char* w = (char*)d_ws;
  float* h        = (float*)(w + o_h);
  u16*   xl       = (u16*)(w + o_xl);
  u16*   xr       = (u16*)(w + o_xr);
  u32*   rel_s    = (u32*)(w + o_rels);
  float* relmean  = (float*)(w + o_relmean);
  int*   counts   = (int*)(w + o_counts);
  int*   rowstart = (int*)(w + o_rowstart);
  int*   cursor   = (int*)(w + o_cursor);
  int*   adj_src  = (int*)(w + o_adjsrc);
  int*   tilesum  = (int*)(w + o_tilesum);
  int*   tileoff  = (int*)(w + o_tileoff);

  hipMemsetAsync(counts, 0, (size_t)N*4, stream);
  hipMemsetAsync(relmean, 0, 64*4, stream);
  k_relmean<<<64, 256, 0, stream>>>(relation, relmean, E);
  k_count<<<(E+255)/256, 256, 0, stream>>>(edges, counts, E, N);
  k_scan_a<<<nT, 256, 0, stream>>>(counts, tilesum, N);
  k_scan_b<<<1, 1024, 0, stream>>>(tilesum, tileoff, nT);
  k_scan_c<<<nT, 1024, 0, stream>>>(counts, tileoff, rowstart, cursor, N);
  k_scatter<<<(E+255)/256, 256, 0, stream>>>(edges, relation, cursor, adj_src, rel_s, E, N);

  k_embed<<<(N+3)/4, 256, 0, stream>>>(nodes, time_emb, type_emb, biway_emb, islink_emb,
                                       proj_w, proj_b, h, N);

  for(int l=0; l<2; l++){
    k_xlr<<<(N+NT-1)/NT, 256, 0, stream>>>(h,
        lin_l_w + (size_t)l*HHID*64, lin_l_b + (size_t)l*HHID,
        lin_r_w + (size_t)l*HHID*64, lin_r_b + (size_t)l*HHID,
        xl, xr, N);
    k_fused<<<8192, 256, 0, stream>>>(rowstart, adj_src, rel_s, relmean,
        lin_e_w + (size_t)l*HHID*16, att + (size_t)l*HEADS*64,
        xl, xr, gat_b + (size_t)l*64,
        h, N,
        (l==1) ? (float*)d_out : (float*)nullptr);
  }
  k_marker<<<1, 64, 0, stream>>>(rowstart, h, (float*)d_out, N, E);
}

// Round 21
// 858.445 us; speedup vs baseline: 1.3866x; 1.0334x over previous
//
#include <hip/hip_runtime.h>

typedef unsigned short u16;
typedef unsigned int u32;

__device__ __forceinline__ float bf2f(u16 u){ union{u32 i; float f;} v; v.i=((u32)u)<<16; return v.f; }
__device__ __forceinline__ float bflo(u32 p){ union{u32 i; float f;} v; v.i=p<<16; return v.f; }
__device__ __forceinline__ float bfhi(u32 p){ union{u32 i; float f;} v; v.i=p&0xffff0000u; return v.f; }
__device__ __forceinline__ u16 f2bf(float x){ union{float f; u32 i;} v; v.f=x; u32 b=v.i;
  return (u16)((b + 0x7fffu + ((b>>16)&1u))>>16); }
__device__ __forceinline__ u32 pk2(float a, float b){ return ((u32)f2bf(b)<<16) | (u32)f2bf(a); }

#define HEADS 4
#define HHID 256   // HEADS*HID
#define NT 16      // nodes per tile in k_xlr

// ---- fill d_out with a float value (diagnostic only) ----
__global__ void TopoAggregator_33217277067466_kernel(float* __restrict__ out, int n, float val){
  for(int i = blockIdx.x*blockDim.x + threadIdx.x; i < n; i += gridDim.x*blockDim.x)
    out[i] = val;
}

// ---- post-hoc invariant marker: touches d_out ONLY on failure ----
__global__ void k_marker(const int* __restrict__ rowstart, const float* __restrict__ h,
                         float* __restrict__ out, int N, int E){
  if(threadIdx.x!=0 || blockIdx.x!=0) return;
  float M = 0.f;
  if(rowstart[N] != E) M = 400.f;
  else {
    int allz = 1;
    for(int i=0;i<128;i++) if(h[i]!=0.f){ allz=0; break; }
    if(allz) M = 500.f;
  }
  if(M != 0.f) out[0] = M;
}

// ---- relation mean over E rows of 16 (f32) ----
__global__ void k_relmean(const float* __restrict__ rel, float* __restrict__ relmean, int E){
  __shared__ float red[256][16];
  float s[16];
#pragma unroll
  for(int j=0;j<16;j++) s[j]=0.f;
  for(int r = blockIdx.x*blockDim.x + threadIdx.x; r < E; r += gridDim.x*blockDim.x){
    const float4* p = (const float4*)(rel + (size_t)r*16);
    float4 a=p[0], b=p[1], c=p[2], d=p[3];
    s[0]+=a.x; s[1]+=a.y; s[2]+=a.z; s[3]+=a.w;
    s[4]+=b.x; s[5]+=b.y; s[6]+=b.z; s[7]+=b.w;
    s[8]+=c.x; s[9]+=c.y; s[10]+=c.z; s[11]+=c.w;
    s[12]+=d.x; s[13]+=d.y; s[14]+=d.z; s[15]+=d.w;
  }
  int tid = threadIdx.x;
#pragma unroll
  for(int j=0;j<16;j++) red[tid][j]=s[j];
  __syncthreads();
  for(int off=128; off>0; off>>=1){
    if(tid<off){
#pragma unroll
      for(int j=0;j<16;j++) red[tid][j]+=red[tid+off][j];
    }
    __syncthreads();
  }
  if(tid<16) atomicAdd(relmean+tid, red[0][tid]*(1.0f/(float)E));
}

// ---- CSR build over REAL edges only (self-loops handled analytically) ----
__global__ void k_count(const int* __restrict__ edges, int* __restrict__ counts, int E, int N){
  int e = blockIdx.x*blockDim.x + threadIdx.x;
  if(e>=E) return;
  int d = edges[E+e];
  if(d<0) d=0; if(d>=N) d=N-1;
  atomicAdd(counts+d, 1);
}

// ---- 3-phase parallel exclusive scan over counts[N] ----
#define STILE 1024
__global__ void k_scan_a(const int* __restrict__ counts, int* __restrict__ tilesum, int N){
  __shared__ int red[256];
  int base = blockIdx.x*STILE;
  int tid = threadIdx.x;
  int s = 0;
  for(int i=tid; i<STILE; i+=256){
    int idx = base + i;
    s += (idx < N) ? counts[idx] : 0;
  }
  red[tid] = s;
  __syncthreads();
  for(int off=128; off>0; off>>=1){
    if(tid<off) red[tid] += red[tid+off];
    __syncthreads();
  }
  if(tid==0) tilesum[blockIdx.x] = red[0];
}

__global__ void k_scan_b(const int* __restrict__ tilesum, int* __restrict__ tileoff, int nT){
  __shared__ int buf[1024];
  int tid = threadIdx.x;
  buf[tid] = (tid < nT) ? tilesum[tid] : 0;
  __syncthreads();
  for(int off=1; off<1024; off<<=1){
    int v = (tid>=off) ? buf[tid-off] : 0;
    __syncthreads();
    buf[tid] += v;
    __syncthreads();
  }
  if(tid < nT) tileoff[tid] = (tid==0) ? 0 : buf[tid-1];
}

__global__ void k_scan_c(const int* __restrict__ counts, const int* __restrict__ tileoff,
                         int* __restrict__ rowstart, int* __restrict__ cursor, int N){
  __shared__ int buf[STILE];
  int base = blockIdx.x*STILE;
  int tid = threadIdx.x;
  int idx = base + tid;
  int c = (idx < N) ? counts[idx] : 0;
  buf[tid] = c;
  __syncthreads();
  for(int off=1; off<1024; off<<=1){
    int v = (tid>=off) ? buf[tid-off] : 0;
    __syncthreads();
    buf[tid] += v;
    __syncthreads();
  }
  int excl = buf[tid] - c + tileoff[blockIdx.x];
  if(idx < N){ rowstart[idx]=excl; cursor[idx]=excl; }
  if(idx == N-1) rowstart[N] = excl + c;
}

// scatter src AND the rel row (packed bf16, CSR order)
__global__ void k_scatter(const int* __restrict__ edges, const float* __restrict__ relation,
                          int* __restrict__ cursor,
                          int* __restrict__ adj_src, u32* __restrict__ rel_s, int E, int N){
  int e = blockIdx.x*blockDim.x + threadIdx.x;
  if(e>=E) return;
  int s = edges[e], d = edges[E+e];
  if(d<0) d=0; if(d>=N) d=N-1;
  int pos = atomicAdd(cursor+d, 1);
  adj_src[pos]=s;
  const float4* rp = (const float4*)(relation + (size_t)e*16);
  float4 q0=rp[0], q1=rp[1], q2=rp[2], q3=rp[3];
  uint4* dst = (uint4*)(rel_s + (size_t)pos*8);
  dst[0] = make_uint4(pk2(q0.x,q0.y), pk2(q0.z,q0.w), pk2(q1.x,q1.y), pk2(q1.z,q1.w));
  dst[1] = make_uint4(pk2(q2.x,q2.y), pk2(q2.z,q2.w), pk2(q3.x,q3.y), pk2(q3.z,q3.w));
}

// ---- embedding + input projection: h[N][64] (f32) ----
__global__ void k_embed(const float* __restrict__ nodes,
                        const float* __restrict__ time_emb, const float* __restrict__ type_emb,
                        const float* __restrict__ biway_emb, const float* __restrict__ islink_emb,
                        const float* __restrict__ projw, const float* __restrict__ projb,
                        float* __restrict__ h, int N){
  __shared__ float W[64][65];
  __shared__ float h0[4][64];
  int tid = threadIdx.x;
  for(int i=tid; i<64*64; i+=256) W[i>>6][i&63] = projw[i];
  __syncthreads();
  int wave = tid>>6, lane = tid&63;
  int node = blockIdx.x*4 + wave;
  if(node<N){
    const float* nr = nodes + (size_t)node*20;
    float v; int c = lane;
    if(c<16){
      int t=(int)nr[0]; t = t<0?0:(t>287?287:t);
      v = time_emb[t*16+c];
    } else if(c<32){
      int ty=(int)nr[1]; ty = ty<0?0:(ty>15?15:ty);
      v = type_emb[ty*16+(c-16)];
    } else if(c<40){
      int bw=(int)nr[2]; bw = bw<0?0:(bw>1?1:bw);
      v = biway_emb[bw*8+(c-32)];
    } else if(c<48){
      int il=(int)nr[3]; il = il<0?0:(il>1?1:il);
      v = islink_emb[il*8+(c-40)];
    } else {
      v = nr[4 + (c-48)];
    }
    h0[wave][lane]=v;
  }
  __syncthreads();
  if(node<N){
    float acc = projb[lane];
#pragma unroll
    for(int k=0;k<64;k++) acc += W[lane][k]*h0[wave][k];
    h[(size_t)node*64+lane]=acc;
  }
}

// ---- xl/xr = h @ {wl,wr}.T + {bl,br}, stored bf16. 16 nodes/block ----
__global__ void k_xlr(const float* __restrict__ h,
                      const float* __restrict__ wl, const float* __restrict__ bl,
                      const float* __restrict__ wr, const float* __restrict__ br,
                      u16* __restrict__ xl, u16* __restrict__ xr, int N){
  __shared__ float hs[NT*64];
  int tid = threadIdx.x;
  int base = blockIdx.x*NT;
  int nvalid = N - base; if(nvalid > NT) nvalid = NT;
  if(nvalid == NT){
    *(float4*)(hs + tid*4) = *(const float4*)(h + (size_t)base*64 + tid*4);
  } else {
    for(int i=tid; i<NT*64; i+=256) hs[i] = (i < nvalid*64) ? h[(size_t)base*64+i] : 0.f;
  }
  __syncthreads();
  int o = tid;   // output channel 0..255
  const float4* wl4 = (const float4*)(wl + (size_t)o*64);
  const float4* wr4 = (const float4*)(wr + (size_t)o*64);
  float blv = bl[o], brv = br[o];
  float accl[NT], accr[NT];
#pragma unroll
  for(int n=0;n<NT;n++){ accl[n]=blv; accr[n]=brv; }
  for(int kk=0; kk<16; kk++){
    float4 a = wl4[kk];
    float4 b = wr4[kk];
#pragma unroll
    for(int n=0;n<NT;n++){
      float4 hv = *(const float4*)(hs + n*64 + kk*4);
      accl[n] += a.x*hv.x + a.y*hv.y + a.z*hv.z + a.w*hv.w;
      accr[n] += b.x*hv.x + b.y*hv.y + b.z*hv.z + b.w*hv.w;
    }
  }
  for(int n=0;n<nvalid;n++){
    xl[(size_t)(base+n)*HHID + o] = f2bf(accl[n]);
    xr[(size_t)(base+n)*HHID + o] = f2bf(accr[n]);
  }
}

// ---- fused per-node (r17 structure + s_setprio around compute) ----
__global__ void __launch_bounds__(256)
k_fused(const int* __restrict__ rowstart, const int* __restrict__ adj_src,
        const u32* __restrict__ rel_s, const float* __restrict__ relmean,
        const float* __restrict__ we, const float* __restrict__ att,
        const u16* __restrict__ xl, const u16* __restrict__ xr,
        const float* __restrict__ gat_b,
        float* __restrict__ h, int N, float* __restrict__ outp){
  __shared__ float weT[16*256];   // [k][ch]
  {
    int tid = threadIdx.x;
    for(int i=tid; i<16*256; i+=256){
      int k = i >> 8, ch = i & 255;
      weT[k*256 + ch] = we[(size_t)ch*16 + k];
    }
  }
  __syncthreads();
  const int lane = threadIdx.x & 63;
  const int sub = lane & 15;
  const int wid = (blockIdx.x*blockDim.x + threadIdx.x) >> 6;
  const int nw  = (gridDim.x*blockDim.x) >> 6;
  const float4* wT4 = (const float4*)weT;   // index: k*64 + lane

  const float4 at4 = *(const float4*)(att + lane*4);

  // self-loop ep (per-wave constant)
  float es0=0.f, es1=0.f, es2=0.f, es3=0.f;
#pragma unroll
  for(int k=0;k<16;k++){
    float rmk = relmean[k];
    float4 w4 = wT4[k*64 + lane];
    es0 += rmk*w4.x; es1 += rmk*w4.y; es2 += rmk*w4.z; es3 += rmk*w4.w;
  }

  for(int node = wid; node < N; node += nw){
    const int lo = rowstart[node], hi = rowstart[node+1];
    uint2 pb = *(const uint2*)(xr + (size_t)node*HHID + lane*4);
    float bv0=bflo(pb.x), bv1=bfhi(pb.x), bv2=bflo(pb.y), bv3=bfhi(pb.y);

    // self-loop initializes online softmax
    float m, den, a0, a1, a2, a3;
    {
      uint2 ps = *(const uint2*)(xl + (size_t)node*HHID + lane*4);
      float sv0=bflo(ps.x), sv1=bfhi(ps.x), sv2=bflo(ps.y), sv3=bfhi(ps.y);
      float c = 0.f;
      {
        float mm;
        mm = sv0 + bv0 + es0; mm = (mm>0.f)?mm:0.2f*mm; c += mm*at4.x;
        mm = sv1 + bv1 + es1; mm = (mm>0.f)?mm:0.2f*mm; c += mm*at4.y;
        mm = sv2 + bv2 + es2; mm = (mm>0.f)?mm:0.2f*mm; c += mm*at4.z;
        mm = sv3 + bv3 + es3; mm = (mm>0.f)?mm:0.2f*mm; c += mm*at4.w;
      }
      c += __shfl_xor(c, 1);
      c += __shfl_xor(c, 2);
      c += __shfl_xor(c, 4);
      c += __shfl_xor(c, 8);
      m = c; den = 1.f;
      a0 = sv0; a1 = sv1; a2 = sv2; a3 = sv3;
    }

    // pipeline prologue: idx(lo), idx(lo+1), data(lo)
    int svB = 0;
    uint4 rqA0 = make_uint4(0,0,0,0), rqA1 = rqA0;
    uint2 paA = make_uint2(0u,0u);
    if(lo < hi){
      int sv = adj_src[lo];
      const uint4* rp = (const uint4*)(rel_s + (size_t)lo*8);
      rqA0 = rp[0]; rqA1 = rp[1];
      paA = *(const uint2*)(xl + (size_t)sv*HHID + lane*4);
    }
    if(lo+1 < hi) svB = adj_src[lo+1];

    for(int p=lo; p<hi; p++){
      // stage 1: data loads for p+1 (index resident in svB)
      uint4 rqB0 = make_uint4(0,0,0,0), rqB1 = rqB0;
      uint2 paB = make_uint2(0u,0u);
      if(p+1 < hi){
        const uint4* rp = (const uint4*)(rel_s + (size_t)(p+1)*8);
        rqB0 = rp[0]; rqB1 = rp[1];
        paB = *(const uint2*)(xl + (size_t)svB*HHID + lane*4);
      }
      // stage 2: index load for p+2
      int svC = 0;
      if(p+2 < hi) svC = adj_src[p+2];

      // stage 3: compute edge p on resident rqA*/paA (LDS weT + VALU)
      __builtin_amdgcn_s_setprio(1);
      float ep0=0.f, ep1=0.f, ep2=0.f, ep3=0.f;
#define EPW(W, KBASE) { \
        float rlo = bflo(W), rhi = bfhi(W); \
        float4 wa = wT4[(KBASE)*64 + lane]; \
        float4 wb = wT4[(KBASE+1)*64 + lane]; \
        ep0 += rlo*wa.x + rhi*wb.x; \
        ep1 += rlo*wa.y + rhi*wb.y; \
        ep2 += rlo*wa.z + rhi*wb.z; \
        ep3 += rlo*wa.w + rhi*wb.w; }
      EPW(rqA0.x, 0)  EPW(rqA0.y, 2)  EPW(rqA0.z, 4)  EPW(rqA0.w, 6)
      EPW(rqA1.x, 8)  EPW(rqA1.y,10)  EPW(rqA1.z,12)  EPW(rqA1.w,14)
#undef EPW

      float av0=bflo(paA.x), av1=bfhi(paA.x), av2=bflo(paA.y), av3=bfhi(paA.y);
      float c = 0.f;
      {
        float mm;
        mm = av0 + bv0 + ep0; mm = (mm>0.f)?mm:0.2f*mm; c += mm*at4.x;
        mm = av1 + bv1 + ep1; mm = (mm>0.f)?mm:0.2f*mm; c += mm*at4.y;
        mm = av2 + bv2 + ep2; mm = (mm>0.f)?mm:0.2f*mm; c += mm*at4.z;
        mm = av3 + bv3 + ep3; mm = (mm>0.f)?mm:0.2f*mm; c += mm*at4.w;
      }
      c += __shfl_xor(c, 1);
      c += __shfl_xor(c, 2);
      c += __shfl_xor(c, 4);
      c += __shfl_xor(c, 8);

      if(c > m){
        float sc = __expf(m - c);
        den *= sc; a0 *= sc; a1 *= sc; a2 *= sc; a3 *= sc;
        m = c;
      }
      float wgt = __expf(c - m);
      den += wgt;
      a0 += wgt*av0; a1 += wgt*av1; a2 += wgt*av2; a3 += wgt*av3;
      __builtin_amdgcn_s_setprio(0);

      // rotate pipeline
      rqA0 = rqB0; rqA1 = rqB1; paA = paB; svB = svC;
    }

    float inv = 1.0f/den;
    float v0=a0*inv, v1=a1*inv, v2=a2*inv, v3=a3*inv;
    v0 += __shfl_xor(v0,16); v0 += __shfl_xor(v0,32);
    v1 += __shfl_xor(v1,16); v1 += __shfl_xor(v1,32);
    v2 += __shfl_xor(v2,16); v2 += __shfl_xor(v2,32);
    v3 += __shfl_xor(v3,16); v3 += __shfl_xor(v3,32);
    if(lane < 16){
      int cb = sub*4;
      float4 hv = *(const float4*)(h + (size_t)node*64 + cb);
      const float4 gb = *(const float4*)(gat_b + cb);
      float o0 = fmaxf(0.25f*v0 + gb.x + hv.x, 0.f);
      float o1 = fmaxf(0.25f*v1 + gb.y + hv.y, 0.f);
      float o2 = fmaxf(0.25f*v2 + gb.z + hv.z, 0.f);
      float o3 = fmaxf(0.25f*v3 + gb.w + hv.w, 0.f);
      *(float4*)(h + (size_t)node*64 + cb) = make_float4(o0,o1,o2,o3);
      if(outp) *(float4*)(outp + (size_t)node*64 + cb) = make_float4(o0,o1,o2,o3);
    }
  }
}

extern "C" void kernel_launch(void* const* d_in, const int* in_sizes, int n_in,
                              void* d_out, int out_size, void* d_ws, size_t ws_size,
                              hipStream_t stream) {
  const float* nodes     = (const float*)d_in[0];
  const int*   edges     = (const int*)d_in[1];
  const float* relation  = (const float*)d_in[2];
  const float* time_emb  = (const float*)d_in[3];
  const float* type_emb  = (const float*)d_in[4];
  const float* biway_emb = (const float*)d_in[5];
  const float* islink_emb= (const float*)d_in[6];
  const float* proj_w    = (const float*)d_in[7];
  const float* proj_b    = (const float*)d_in[8];
  const float* lin_l_w   = (const float*)d_in[9];
  const float* lin_l_b   = (const float*)d_in[10];
  const float* lin_r_w   = (const float*)d_in[11];
  const float* lin_r_b   = (const float*)d_in[12];
  const float* lin_e_w   = (const float*)d_in[13];
  const float* att       = (const float*)d_in[14];
  const float* gat_b     = (const float*)d_in[15];

  const int N  = in_sizes[0] / 20;
  const int E  = in_sizes[1] / 2;
  const int nT = (N + STILE - 1) / STILE;

  size_t off = 0;
  auto alloc = [&](size_t bytes)->size_t {
    size_t p = off;
    off += ((bytes + 255) / 256) * 256;
    return p;
  };
  size_t o_h        = alloc((size_t)N*64*4);        // f32
  size_t o_xl       = alloc((size_t)N*HHID*2);      // bf16
  size_t o_xr       = alloc((size_t)N*HHID*2);      // bf16
  size_t o_rels     = alloc((size_t)E*32);          // bf16 rel rows, CSR order
  size_t o_relmean  = alloc(64*4);
  size_t o_counts   = alloc((size_t)N*4);
  size_t o_rowstart = alloc((size_t)(N+1)*4);
  size_t o_cursor   = alloc((size_t)(N+1)*4);
  size_t o_adjsrc   = alloc((size_t)E*4);
  size_t o_tilesum  = alloc((size_t)nT*4);
  size_t o_tileoff  = alloc((size_t)nT*4);

  if (off > ws_size) {
    TopoAggregator_33217277067466_kernel<<<2048, 256, 0, stream>>>(
        (float*)d_out, out_size, 100.0f);
    return;
  }

  char* w = (char*)d_ws;
  float* h        = (float*)(w + o_h);
  u16*   xl       = (u16*)(w + o_xl);
  u16*   xr       = (u16*)(w + o_xr);
  u32*   rel_s    = (u32*)(w + o_rels);
  float* relmean  = (float*)(w + o_relmean);
  int*   counts   = (int*)(w + o_counts);
  int*   rowstart = (int*)(w + o_rowstart);
  int*   cursor   = (int*)(w + o_cursor);
  int*   adj_src  = (int*)(w + o_adjsrc);
  int*   tilesum  = (int*)(w + o_tilesum);
  int*   tileoff  = (int*)(w + o_tileoff);

  hipMemsetAsync(counts, 0, (size_t)N*4, stream);
  hipMemsetAsync(relmean, 0, 64*4, stream);
  k_relmean<<<64, 256, 0, stream>>>(relation, relmean, E);
  k_count<<<(E+255)/256, 256, 0, stream>>>(edges, counts, E, N);
  k_scan_a<<<nT, 256, 0, stream>>>(counts, tilesum, N);
  k_scan_b<<<1, 1024, 0, stream>>>(tilesum, tileoff, nT);
  k_scan_c<<<nT, 1024, 0, stream>>>(counts, tileoff, rowstart, cursor, N);
  k_scatter<<<(E+255)/256, 256, 0, stream>>>(edges, relation, cursor, adj_src, rel_s, E, N);

  k_embed<<<(N+3)/4, 256, 0, stream>>>(nodes, time_emb, type_emb, biway_emb, islink_emb,
                                       proj_w, proj_b, h, N);

  for(int l=0; l<2; l++){
    k_xlr<<<(N+NT-1)/NT, 256, 0, stream>>>(h,
        lin_l_w + (size_t)l*HHID*64, lin_l_b + (size_t)l*HHID,
        lin_r_w + (size_t)l*HHID*64, lin_r_b + (size_t)l*HHID,
        xl, xr, N);
    k_fused<<<4096, 256, 0, stream>>>(rowstart, adj_src, rel_s, relmean,
        lin_e_w + (size_t)l*HHID*16, att + (size_t)l*HEADS*64,
        xl, xr, gat_b + (size_t)l*64,
        h, N,
        (l==1) ? (float*)d_out : (float*)nullptr);
  }
  k_marker<<<1, 64, 0, stream>>>(rowstart, h, (float*)d_out, N, E);
}